// Round 3
// baseline (222.310 us; speedup 1.0000x reference)
//
#include <hip/hip_runtime.h>

// Pipeline: cvt(x,Wqkv,Wproj) -> GEMM qkv(bf16, global_load_lds) -> norm/split ->
//           bias_prep -> v_transpose -> flash attn (swapped-QK^T, fixed-max softmax)
//           -> GEMM proj(f32+bias)
// B=2 L=2048 C=1024 H=16 D=64. All matmuls bf16 MFMA 16x16x32, f32 accumulate.

typedef __bf16 bf16x8 __attribute__((ext_vector_type(8)));
typedef __bf16 bf16x4 __attribute__((ext_vector_type(4)));
typedef float  f32x4  __attribute__((ext_vector_type(4)));

#define BB 2
#define LL 2048
#define CC 1024
#define HH 16
#define DD 64
#define LOG2E 1.44269504088896f

__device__ __forceinline__ f32x4 mfma_16x16x32(bf16x8 a, bf16x8 b, f32x4 c) {
    return __builtin_amdgcn_mfma_f32_16x16x32_bf16(a, b, c, 0, 0, 0);
}

// async global->LDS, 16B per lane; lds dest must be wave-uniform base (lane*16 auto)
__device__ __forceinline__ void gload_lds16(const __bf16* g, __bf16* lds) {
    __builtin_amdgcn_global_load_lds(
        (const __attribute__((address_space(1))) unsigned int*)g,
        (__attribute__((address_space(3))) unsigned int*)lds,
        16, 0, 0);
}

// ---------------- f32 -> bf16 convert ----------------
__global__ __launch_bounds__(256) void cvt_bf16_kernel(const float* __restrict__ in,
                                                       __bf16* __restrict__ out, int n4) {
    int i = blockIdx.x * 256 + threadIdx.x;
    if (i >= n4) return;
    float4 v = reinterpret_cast<const float4*>(in)[i];
    bf16x4 o;
    o[0] = (__bf16)v.x; o[1] = (__bf16)v.y; o[2] = (__bf16)v.z; o[3] = (__bf16)v.w;
    reinterpret_cast<bf16x4*>(out)[i] = o;
}

// ---------------- bias prep: rowmax + bf16(bias - rowmax) ----------------
__global__ __launch_bounds__(256) void bias_prep_kernel(const float* __restrict__ bias,
                                                        __bf16* __restrict__ bias_bf) {
    __shared__ float wmax[4];
    const int l = blockIdx.x, tid = threadIdx.x;
    const int w = tid >> 6;
    float4 a = reinterpret_cast<const float4*>(bias + (size_t)l * 2048)[tid];
    float4 b = reinterpret_cast<const float4*>(bias + (size_t)l * 2048 + 1024)[tid];
    float m = fmaxf(fmaxf(fmaxf(a.x, a.y), fmaxf(a.z, a.w)),
                    fmaxf(fmaxf(b.x, b.y), fmaxf(b.z, b.w)));
#pragma unroll
    for (int off = 1; off < 64; off <<= 1) m = fmaxf(m, __shfl_xor(m, off, 64));
    if ((tid & 63) == 0) wmax[w] = m;
    __syncthreads();
    float M = fmaxf(fmaxf(wmax[0], wmax[1]), fmaxf(wmax[2], wmax[3]));
    bf16x4 o0, o1;
    o0[0] = (__bf16)(a.x - M); o0[1] = (__bf16)(a.y - M);
    o0[2] = (__bf16)(a.z - M); o0[3] = (__bf16)(a.w - M);
    o1[0] = (__bf16)(b.x - M); o1[1] = (__bf16)(b.y - M);
    o1[2] = (__bf16)(b.z - M); o1[3] = (__bf16)(b.w - M);
    reinterpret_cast<bf16x4*>(bias_bf + (size_t)l * 2048)[tid] = o0;
    reinterpret_cast<bf16x4*>(bias_bf + (size_t)l * 2048 + 1024)[tid] = o1;
}

// ---------------- GEMM: C[M,N] = A[M,K] * B[N,K]^T (+bias), m97-style staging ----------------
template <int OUT_MODE>
__global__ __launch_bounds__(256) void gemm_bt_kernel(
    const __bf16* __restrict__ A, const __bf16* __restrict__ Bm,
    float* __restrict__ Cf, __bf16* __restrict__ Cb,
    const float* __restrict__ bias, int M, int N, int K) {
    __shared__ __bf16 As[128][64];   // linear (global_load_lds requires contiguous dest)
    __shared__ __bf16 Bs[128][64];
    const int tid = threadIdx.x;
    const int m0 = blockIdx.x * 128, n0 = blockIdx.y * 128;
    const int w  = tid >> 6, l = tid & 63;
    const int wr = (w >> 1) * 64, wc = (w & 1) * 64;
    const int lr = l & 15, lg = l >> 4;
    f32x4 acc[4][4] = {};
    // staging: wave w covers rows w*32..w*32+31, 4 issues of (8 rows x 64 cols)
    const int srow = w * 32 + (l >> 3);
    const int scol = (l & 7) * 8;
    const __bf16* ag = A  + (size_t)(m0 + srow) * K + scol;
    const __bf16* bg = Bm + (size_t)(n0 + srow) * K + scol;

    for (int kt = 0; kt < K; kt += 64) {
        __syncthreads();
#pragma unroll
        for (int i = 0; i < 4; ++i) {
            gload_lds16(ag + kt + (size_t)(i * 8) * K, &As[w * 32 + i * 8][0]);
            gload_lds16(bg + kt + (size_t)(i * 8) * K, &Bs[w * 32 + i * 8][0]);
        }
        asm volatile("s_waitcnt vmcnt(0)" ::: "memory");
        __syncthreads();
#pragma unroll
        for (int kk = 0; kk < 64; kk += 32) {
            bf16x8 af[4], bfr[4];
#pragma unroll
            for (int m = 0; m < 4; ++m)
                af[m] = *reinterpret_cast<const bf16x8*>(&As[wr + m * 16 + lr][kk + lg * 8]);
#pragma unroll
            for (int n = 0; n < 4; ++n)
                bfr[n] = *reinterpret_cast<const bf16x8*>(&Bs[wc + n * 16 + lr][kk + lg * 8]);
#pragma unroll
            for (int m = 0; m < 4; ++m)
#pragma unroll
                for (int n = 0; n < 4; ++n)
                    acc[m][n] = mfma_16x16x32(af[m], bfr[n], acc[m][n]);
        }
    }
#pragma unroll
    for (int m = 0; m < 4; ++m) {
#pragma unroll
        for (int n = 0; n < 4; ++n) {
            const int row = m0 + wr + m * 16 + lg * 4;
            const int col = n0 + wc + n * 16 + lr;
#pragma unroll
            for (int r = 0; r < 4; ++r) {
                float v = acc[m][n][r];
                if (OUT_MODE == 0) {
                    Cb[(size_t)(row + r) * N + col] = (__bf16)v;
                } else {
                    Cf[(size_t)(row + r) * N + col] = v + bias[col];
                }
            }
        }
    }
}

// ---------------- bias add + l2norm + scale, split into Q/K/V (B,H,L,D) bf16 ----------------
__global__ __launch_bounds__(256) void qkv_norm_kernel(
    const __bf16* __restrict__ qkv, const float* __restrict__ q_bias,
    const float* __restrict__ v_bias, const float* __restrict__ scale_mul,
    __bf16* __restrict__ Q, __bf16* __restrict__ K, __bf16* __restrict__ V) {
    const int bl = blockIdx.x;
    const int tid = threadIdx.x;
    const int w = tid >> 6, d = tid & 63;
    const int b = bl >> 11, l = bl & 2047;
    for (int g = w; g < 48; g += 4) {
        const int s = g >> 4, h = g & 15;
        float v = (float)qkv[(size_t)bl * 3072 + g * 64 + d];
        if (s == 0) v += q_bias[h * 64 + d];
        if (s == 2) v += v_bias[h * 64 + d];
        if (s < 2) {
            float ss = v * v;
#pragma unroll
            for (int off = 1; off < 64; off <<= 1) ss += __shfl_xor(ss, off, 64);
            float nrm = sqrtf(ss);
            v = v / fmaxf(nrm, 1e-12f);
            if (s == 0) v *= __expf(fminf(scale_mul[h], 4.60517019f));
        }
        __bf16* dst = (s == 0) ? Q : ((s == 1) ? K : V);
        dst[((size_t)(b * 16 + h) * 2048 + l) * 64 + d] = (__bf16)v;
    }
}

// ---------------- V transpose: (B,H,L,D) -> (B,H,D,L) ----------------
__global__ __launch_bounds__(256) void v_transpose_kernel(const __bf16* __restrict__ Vin,
                                                          __bf16* __restrict__ Vt) {
    __shared__ __bf16 T[64][72];
    const int lb = blockIdx.x, bh = blockIdx.y;
    const int tid = threadIdx.x;
    const size_t base = (size_t)bh * LL * DD;
    const int row = tid >> 2, c = (tid & 3) * 16;
    {
        const __bf16* src = Vin + base + (size_t)(lb * 64 + row) * 64 + c;
        *reinterpret_cast<bf16x8*>(&T[row][c])     = *reinterpret_cast<const bf16x8*>(src);
        *reinterpret_cast<bf16x8*>(&T[row][c + 8]) = *reinterpret_cast<const bf16x8*>(src + 8);
    }
    __syncthreads();
    bf16x8 o0, o1;
#pragma unroll
    for (int j = 0; j < 8; ++j) {
        o0[j] = T[c + j][row];
        o1[j] = T[c + 8 + j][row];
    }
    __bf16* dst = Vt + base + (size_t)row * 2048 + lb * 64 + c;
    *reinterpret_cast<bf16x8*>(dst)     = o0;
    *reinterpret_cast<bf16x8*>(dst + 8) = o1;
}

// ---------------- flash attention, swapped QK^T + fixed-max softmax ----------------
// grid (bh=32, qb=32); 256 threads = 4 waves, wave w owns q-rows [qb*64+w*16, +16).
// S^T = mfma(K, Q): lane holds q = w*16+lr (fixed), k = t*16+lg*4+r.
__global__ __launch_bounds__(256) void attn_kernel(
    const __bf16* __restrict__ Q, const __bf16* __restrict__ K,
    const __bf16* __restrict__ Vt, const __bf16* __restrict__ bias_bf,
    const float* __restrict__ scale_mul, __bf16* __restrict__ Octx) {
    __shared__ __bf16 Ks[64][72];
    __shared__ __bf16 Vs[64][72];   // Vs[d][k]
    __shared__ __bf16 Ps[64][72];   // Ps[q_local][k]
    const int bh = blockIdx.x, qb = blockIdx.y;
    const int tid = threadIdx.x;
    const int w = tid >> 6, l = tid & 63;
    const int lr = l & 15, lg = l >> 4;
    const int b = bh >> 4, h = bh & 15;
    const size_t base = (size_t)bh * LL * DD;
    const float smh = __expf(fminf(scale_mul[h], 4.60517019f));
    const float cexp = -smh * LOG2E;

    const int gq = qb * 64 + w * 16 + lr;   // this lane's q row (global within L)
    bf16x8 qf[2];
    qf[0] = *reinterpret_cast<const bf16x8*>(Q + base + (size_t)gq * 64 + lg * 8);
    qf[1] = *reinterpret_cast<const bf16x8*>(Q + base + (size_t)gq * 64 + 32 + lg * 8);
    const __bf16* brow = bias_bf + (size_t)gq * 2048;

    f32x4 Oa[4] = {};
    float lsum = 0.f;
    const int srow = tid >> 2, sc = (tid & 3) * 16;

    for (int kb = 0; kb < 32; ++kb) {
        __syncthreads();
        {
            const __bf16* kg = K + base + (size_t)(kb * 64 + srow) * 64 + sc;
            *reinterpret_cast<bf16x8*>(&Ks[srow][sc])     = *reinterpret_cast<const bf16x8*>(kg);
            *reinterpret_cast<bf16x8*>(&Ks[srow][sc + 8]) = *reinterpret_cast<const bf16x8*>(kg + 8);
            const __bf16* vg = Vt + base + (size_t)srow * 2048 + kb * 64 + sc;
            *reinterpret_cast<bf16x8*>(&Vs[srow][sc])     = *reinterpret_cast<const bf16x8*>(vg);
            *reinterpret_cast<bf16x8*>(&Vs[srow][sc + 8]) = *reinterpret_cast<const bf16x8*>(vg + 8);
        }
        __syncthreads();

        // S^T = K Q^T : sa[t] rows = k (t*16+lg*4+r), col = q (lr)
        f32x4 sa[4] = {};
#pragma unroll
        for (int t = 0; t < 4; ++t) {
            bf16x8 kf0 = *reinterpret_cast<const bf16x8*>(&Ks[t * 16 + lr][lg * 8]);
            bf16x8 kf1 = *reinterpret_cast<const bf16x8*>(&Ks[t * 16 + lr][32 + lg * 8]);
            sa[t] = mfma_16x16x32(kf0, qf[0], sa[t]);
            sa[t] = mfma_16x16x32(kf1, qf[1], sa[t]);
        }

        // softmax: p = exp2((s+bias)·log2e − smh·log2e); exponent ≤ ~0.006·smh, safe.
#pragma unroll
        for (int t = 0; t < 4; ++t) {
            bf16x4 bv = *reinterpret_cast<const bf16x4*>(brow + kb * 64 + t * 16 + lg * 4);
            bf16x4 pb;
#pragma unroll
            for (int r = 0; r < 4; ++r) {
                float s = sa[t][r] + (float)bv[r];
                float p = exp2f(fmaf(s, LOG2E, cexp));
                lsum += p;
                pb[r] = (__bf16)p;
            }
            *reinterpret_cast<bf16x4*>(&Ps[w * 16 + lr][t * 16 + lg * 4]) = pb;
        }

        // O += P·V (Ps rows are wave-private; same-wave LDS dep handled by lgkmcnt)
        bf16x8 pf0 = *reinterpret_cast<const bf16x8*>(&Ps[w * 16 + lr][lg * 8]);
        bf16x8 pf1 = *reinterpret_cast<const bf16x8*>(&Ps[w * 16 + lr][32 + lg * 8]);
#pragma unroll
        for (int t = 0; t < 4; ++t) {
            bf16x8 vf0 = *reinterpret_cast<const bf16x8*>(&Vs[t * 16 + lr][lg * 8]);
            bf16x8 vf1 = *reinterpret_cast<const bf16x8*>(&Vs[t * 16 + lr][32 + lg * 8]);
            Oa[t] = mfma_16x16x32(pf0, vf0, Oa[t]);
            Oa[t] = mfma_16x16x32(pf1, vf1, Oa[t]);
        }
    }

    // reduce lsum over the 4 lg-groups holding partial sums for each q
    lsum += __shfl_xor(lsum, 16, 64);
    lsum += __shfl_xor(lsum, 32, 64);
    float inv[4];
#pragma unroll
    for (int r = 0; r < 4; ++r) inv[r] = 1.0f / __shfl(lsum, lg * 4 + r, 64);

#pragma unroll
    for (int t = 0; t < 4; ++t)
#pragma unroll
        for (int r = 0; r < 4; ++r) {
            const int row = qb * 64 + w * 16 + lg * 4 + r;
            float o = Oa[t][r] * inv[r];
            Octx[((size_t)(b * 2048 + row)) * 1024 + h * 64 + t * 16 + lr] = (__bf16)o;
        }
}

// ---------------- launch ----------------
extern "C" void kernel_launch(void* const* d_in, const int* in_sizes, int n_in,
                              void* d_out, int out_size, void* d_ws, size_t ws_size,
                              hipStream_t stream) {
    const float* x         = (const float*)d_in[0];
    const float* attn_bias = (const float*)d_in[1];
    const float* W_qkv     = (const float*)d_in[2];
    const float* q_bias    = (const float*)d_in[3];
    const float* v_bias    = (const float*)d_in[4];
    const float* scale_mul = (const float*)d_in[5];
    const float* W_proj    = (const float*)d_in[6];
    const float* b_proj    = (const float*)d_in[7];
    float* out = (float*)d_out;

    char* ws = (char*)d_ws;
    size_t off = 0;
    auto alloc = [&](size_t bytes) {
        void* p = ws + off;
        off = (off + bytes + 255) & ~(size_t)255;
        return p;
    };
    __bf16* xb     = (__bf16*)alloc((size_t)4096 * 1024 * 2);
    __bf16* wqkvb  = (__bf16*)alloc((size_t)3072 * 1024 * 2);
    __bf16* wprojb = (__bf16*)alloc((size_t)1024 * 1024 * 2);
    __bf16* qkvb   = (__bf16*)alloc((size_t)4096 * 3072 * 2);   // 24 MB
    __bf16* Qw     = (__bf16*)alloc((size_t)BB * HH * LL * DD * 2);
    __bf16* Kw     = (__bf16*)alloc((size_t)BB * HH * LL * DD * 2);
    __bf16* Vw     = (__bf16*)alloc((size_t)BB * HH * LL * DD * 2);
    __bf16* Oc     = (__bf16*)alloc((size_t)4096 * 1024 * 2);
    // alias: after qkv_norm consumes qkvb, reuse its space for bias_bf and Vt
    __bf16* bias_bf = qkvb;                                      // 8 MB
    __bf16* Vt      = qkvb + (size_t)2048 * 2048;                // 8 MB

    cvt_bf16_kernel<<<4096, 256, 0, stream>>>(x, xb, 4096 * 1024 / 4);
    cvt_bf16_kernel<<<3072, 256, 0, stream>>>(W_qkv, wqkvb, 3072 * 1024 / 4);
    cvt_bf16_kernel<<<1024, 256, 0, stream>>>(W_proj, wprojb, 1024 * 1024 / 4);

    gemm_bt_kernel<0><<<dim3(32, 24), 256, 0, stream>>>(
        xb, wqkvb, nullptr, qkvb, nullptr, 4096, 3072, 1024);

    qkv_norm_kernel<<<4096, 256, 0, stream>>>(qkvb, q_bias, v_bias, scale_mul, Qw, Kw, Vw);

    bias_prep_kernel<<<2048, 256, 0, stream>>>(attn_bias, bias_bf);
    v_transpose_kernel<<<dim3(32, 32), 256, 0, stream>>>(Vw, Vt);

    attn_kernel<<<dim3(32, 32), 256, 0, stream>>>(Qw, Kw, Vt, bias_bf, scale_mul, Oc);

    gemm_bt_kernel<1><<<dim3(32, 8), 256, 0, stream>>>(
        Oc, wprojb, out, nullptr, b_proj, 4096, 1024, 1024);
}

// Round 4
// 196.908 us; speedup vs baseline: 1.1290x; 1.1290x over previous
//
#include <hip/hip_runtime.h>

// Pipeline: cvt(x,Wqkv,Wproj) -> GEMM qkv(bf16) -> norm/split -> bias_prep ->
//           v_transpose -> flash attn (swapped-QK^T, dbuf, 1 barrier/iter, XOR-swizzled LDS)
//           -> GEMM proj(f32+bias)
// B=2 L=2048 C=1024 H=16 D=64. All matmuls bf16 MFMA 16x16x32, f32 accumulate.

typedef __bf16 bf16x8 __attribute__((ext_vector_type(8)));
typedef __bf16 bf16x4 __attribute__((ext_vector_type(4)));
typedef float  f32x4  __attribute__((ext_vector_type(4)));

#define BB 2
#define LL 2048
#define CC 1024
#define HH 16
#define DD 64
#define LOG2E 1.44269504088896f

__device__ __forceinline__ f32x4 mfma_16x16x32(bf16x8 a, bf16x8 b, f32x4 c) {
    return __builtin_amdgcn_mfma_f32_16x16x32_bf16(a, b, c, 0, 0, 0);
}

// ---------------- f32 -> bf16 convert ----------------
__global__ __launch_bounds__(256) void cvt_bf16_kernel(const float* __restrict__ in,
                                                       __bf16* __restrict__ out, int n4) {
    int i = blockIdx.x * 256 + threadIdx.x;
    if (i >= n4) return;
    float4 v = reinterpret_cast<const float4*>(in)[i];
    bf16x4 o;
    o[0] = (__bf16)v.x; o[1] = (__bf16)v.y; o[2] = (__bf16)v.z; o[3] = (__bf16)v.w;
    reinterpret_cast<bf16x4*>(out)[i] = o;
}

// ---------------- bias prep: rowmax + bf16(bias - rowmax) ----------------
__global__ __launch_bounds__(256) void bias_prep_kernel(const float* __restrict__ bias,
                                                        __bf16* __restrict__ bias_bf) {
    __shared__ float wmax[4];
    const int l = blockIdx.x, tid = threadIdx.x;
    const int w = tid >> 6;
    float4 a = reinterpret_cast<const float4*>(bias + (size_t)l * 2048)[tid];
    float4 b = reinterpret_cast<const float4*>(bias + (size_t)l * 2048 + 1024)[tid];
    float m = fmaxf(fmaxf(fmaxf(a.x, a.y), fmaxf(a.z, a.w)),
                    fmaxf(fmaxf(b.x, b.y), fmaxf(b.z, b.w)));
#pragma unroll
    for (int off = 1; off < 64; off <<= 1) m = fmaxf(m, __shfl_xor(m, off, 64));
    if ((tid & 63) == 0) wmax[w] = m;
    __syncthreads();
    float M = fmaxf(fmaxf(wmax[0], wmax[1]), fmaxf(wmax[2], wmax[3]));
    bf16x4 o0, o1;
    o0[0] = (__bf16)(a.x - M); o0[1] = (__bf16)(a.y - M);
    o0[2] = (__bf16)(a.z - M); o0[3] = (__bf16)(a.w - M);
    o1[0] = (__bf16)(b.x - M); o1[1] = (__bf16)(b.y - M);
    o1[2] = (__bf16)(b.z - M); o1[3] = (__bf16)(b.w - M);
    reinterpret_cast<bf16x4*>(bias_bf + (size_t)l * 2048)[tid] = o0;
    reinterpret_cast<bf16x4*>(bias_bf + (size_t)l * 2048 + 1024)[tid] = o1;
}

// ---------------- GEMM: C[M,N] = A[M,K] * B[N,K]^T (+bias), XOR-swizzled LDS ----------------
template <int OUT_MODE>
__global__ __launch_bounds__(256) void gemm_bt_kernel(
    const __bf16* __restrict__ A, const __bf16* __restrict__ Bm,
    float* __restrict__ Cf, __bf16* __restrict__ Cb,
    const float* __restrict__ bias, int M, int N, int K) {
    __shared__ __bf16 As[128 * 64];   // linear, XOR-swizzled (byte ^= (row&7)<<4)
    __shared__ __bf16 Bs[128 * 64];
    const int tid = threadIdx.x;
    const int m0 = blockIdx.x * 128, n0 = blockIdx.y * 128;
    const int w  = tid >> 6, l = tid & 63;
    const int wr = (w >> 1) * 64, wc = (w & 1) * 64;
    const int lr = l & 15, lg = l >> 4;
    const int rmask = (lr & 7) << 4;            // read-side swizzle (rows ≡ lr mod 8)
    f32x4 acc[4][4] = {};
    const int srow = tid >> 1;
    const int scb  = (tid & 1) * 64;            // byte col base within 128B row
    const int smask = (srow & 7) << 4;
    const __bf16* ag = A  + (size_t)(m0 + srow) * K + (tid & 1) * 32;
    const __bf16* bg = Bm + (size_t)(n0 + srow) * K + (tid & 1) * 32;
    char* asb = (char*)As + srow * 128;
    char* bsb = (char*)Bs + srow * 128;

    for (int kt = 0; kt < K; kt += 64) {
        bf16x8 av[4], bv[4];
#pragma unroll
        for (int j = 0; j < 4; ++j) {
            av[j] = *reinterpret_cast<const bf16x8*>(ag + kt + j * 8);
            bv[j] = *reinterpret_cast<const bf16x8*>(bg + kt + j * 8);
        }
        __syncthreads();
#pragma unroll
        for (int j = 0; j < 4; ++j) {
            *reinterpret_cast<bf16x8*>(asb + ((scb + j * 16) ^ smask)) = av[j];
            *reinterpret_cast<bf16x8*>(bsb + ((scb + j * 16) ^ smask)) = bv[j];
        }
        __syncthreads();
#pragma unroll
        for (int kk = 0; kk < 2; ++kk) {        // kk*64 bytes
            bf16x8 af[4], bfr[4];
#pragma unroll
            for (int m = 0; m < 4; ++m)
                af[m] = *reinterpret_cast<const bf16x8*>(
                    (char*)As + (wr + m * 16 + lr) * 128 + ((kk * 64 + lg * 16) ^ rmask));
#pragma unroll
            for (int n = 0; n < 4; ++n)
                bfr[n] = *reinterpret_cast<const bf16x8*>(
                    (char*)Bs + (wc + n * 16 + lr) * 128 + ((kk * 64 + lg * 16) ^ rmask));
#pragma unroll
            for (int m = 0; m < 4; ++m)
#pragma unroll
                for (int n = 0; n < 4; ++n)
                    acc[m][n] = mfma_16x16x32(af[m], bfr[n], acc[m][n]);
        }
    }
#pragma unroll
    for (int m = 0; m < 4; ++m) {
#pragma unroll
        for (int n = 0; n < 4; ++n) {
            const int row = m0 + wr + m * 16 + lg * 4;
            const int col = n0 + wc + n * 16 + lr;
#pragma unroll
            for (int r = 0; r < 4; ++r) {
                float v = acc[m][n][r];
                if (OUT_MODE == 0) {
                    Cb[(size_t)(row + r) * N + col] = (__bf16)v;
                } else {
                    Cf[(size_t)(row + r) * N + col] = v + bias[col];
                }
            }
        }
    }
}

// ---------------- bias add + l2norm + scale, split into Q/K/V (B,H,L,D) bf16 ----------------
__global__ __launch_bounds__(256) void qkv_norm_kernel(
    const __bf16* __restrict__ qkv, const float* __restrict__ q_bias,
    const float* __restrict__ v_bias, const float* __restrict__ scale_mul,
    __bf16* __restrict__ Q, __bf16* __restrict__ K, __bf16* __restrict__ V) {
    const int bl = blockIdx.x;
    const int tid = threadIdx.x;
    const int w = tid >> 6, d = tid & 63;
    const int b = bl >> 11, l = bl & 2047;
    for (int g = w; g < 48; g += 4) {
        const int s = g >> 4, h = g & 15;
        float v = (float)qkv[(size_t)bl * 3072 + g * 64 + d];
        if (s == 0) v += q_bias[h * 64 + d];
        if (s == 2) v += v_bias[h * 64 + d];
        if (s < 2) {
            float ss = v * v;
#pragma unroll
            for (int off = 1; off < 64; off <<= 1) ss += __shfl_xor(ss, off, 64);
            float nrm = sqrtf(ss);
            v = v / fmaxf(nrm, 1e-12f);
            if (s == 0) v *= __expf(fminf(scale_mul[h], 4.60517019f));
        }
        __bf16* dst = (s == 0) ? Q : ((s == 1) ? K : V);
        dst[((size_t)(b * 16 + h) * 2048 + l) * 64 + d] = (__bf16)v;
    }
}

// ---------------- V transpose: (B,H,L,D) -> (B,H,D,L) ----------------
__global__ __launch_bounds__(256) void v_transpose_kernel(const __bf16* __restrict__ Vin,
                                                          __bf16* __restrict__ Vt) {
    __shared__ __bf16 T[64][72];
    const int lb = blockIdx.x, bh = blockIdx.y;
    const int tid = threadIdx.x;
    const size_t base = (size_t)bh * LL * DD;
    const int row = tid >> 2, c = (tid & 3) * 16;
    {
        const __bf16* src = Vin + base + (size_t)(lb * 64 + row) * 64 + c;
        *reinterpret_cast<bf16x8*>(&T[row][c])     = *reinterpret_cast<const bf16x8*>(src);
        *reinterpret_cast<bf16x8*>(&T[row][c + 8]) = *reinterpret_cast<const bf16x8*>(src + 8);
    }
    __syncthreads();
    bf16x8 o0, o1;
#pragma unroll
    for (int j = 0; j < 8; ++j) {
        o0[j] = T[c + j][row];
        o1[j] = T[c + 8 + j][row];
    }
    __bf16* dst = Vt + base + (size_t)row * 2048 + lb * 64 + c;
    *reinterpret_cast<bf16x8*>(dst)     = o0;
    *reinterpret_cast<bf16x8*>(dst + 8) = o1;
}

// ---------------- flash attention: swapped QK^T, fixed-max softmax,
//                  double-buffered K/V (reg-staged), 1 barrier/iter, XOR-swizzled LDS ----
// grid (bh=32, qb=32); 256 threads = 4 waves, wave w owns q-rows [qb*64+w*16, +16).
__global__ __launch_bounds__(256) void attn_kernel(
    const __bf16* __restrict__ Q, const __bf16* __restrict__ K,
    const __bf16* __restrict__ Vt, const __bf16* __restrict__ bias_bf,
    const float* __restrict__ scale_mul, __bf16* __restrict__ Octx) {
    __shared__ __bf16 KVs[2][2][64 * 64];   // [buf][K/V], linear + XOR swizzle
    __shared__ __bf16 Ps[64 * 64];          // [q_local][k], wave-private rows
    const int bh = blockIdx.x, qb = blockIdx.y;
    const int tid = threadIdx.x;
    const int w = tid >> 6, l = tid & 63;
    const int lr = l & 15, lg = l >> 4;
    const int rmask = (lr & 7) << 4;
    const int b = bh >> 4, h = bh & 15;
    const size_t base = (size_t)bh * LL * DD;
    const float smh = __expf(fminf(scale_mul[h], 4.60517019f));
    const float cexp = -smh * LOG2E;

    const int gq = qb * 64 + w * 16 + lr;   // this lane's q row
    bf16x8 qf[2];
    qf[0] = *reinterpret_cast<const bf16x8*>(Q + base + (size_t)gq * 64 + lg * 8);
    qf[1] = *reinterpret_cast<const bf16x8*>(Q + base + (size_t)gq * 64 + 32 + lg * 8);
    const __bf16* brow = bias_bf + (size_t)gq * 2048;

    // staging geometry: 4 threads per row, 32B chunks
    const int srow = tid >> 2;
    const int scb  = (tid & 3) * 32;               // byte col base
    const int smask = (srow & 7) << 4;
    const __bf16* kgbase = K  + base + (size_t)srow * 64   + (tid & 3) * 16;
    const __bf16* vgbase = Vt + base + (size_t)srow * 2048 + (tid & 3) * 16;

    bf16x8 k0, k1, v0, v1;
    auto stage_regs = [&](int kb) {
        const __bf16* kg = kgbase + (size_t)kb * 64 * 64;
        k0 = *reinterpret_cast<const bf16x8*>(kg);
        k1 = *reinterpret_cast<const bf16x8*>(kg + 8);
        const __bf16* vg = vgbase + kb * 64;
        v0 = *reinterpret_cast<const bf16x8*>(vg);
        v1 = *reinterpret_cast<const bf16x8*>(vg + 8);
    };
    auto write_lds = [&](int buf) {
        char* kp = (char*)KVs[buf][0] + srow * 128;
        char* vp = (char*)KVs[buf][1] + srow * 128;
        *reinterpret_cast<bf16x8*>(kp + (scb ^ smask))        = k0;
        *reinterpret_cast<bf16x8*>(kp + ((scb + 16) ^ smask)) = k1;
        *reinterpret_cast<bf16x8*>(vp + (scb ^ smask))        = v0;
        *reinterpret_cast<bf16x8*>(vp + ((scb + 16) ^ smask)) = v1;
    };

    stage_regs(0);
    write_lds(0);

    f32x4 Oa[4] = {};
    float lsum = 0.f;
    int cur = 0;
    char* psb = (char*)Ps + (w * 16 + lr) * 128;

    for (int kb = 0; kb < 32; ++kb) {
        __syncthreads();                 // buf[cur] ready; buf[cur^1] free
        if (kb < 31) stage_regs(kb + 1); // issue early, consume late (T14)

        const char* Kc = (const char*)KVs[cur][0];
        const char* Vc = (const char*)KVs[cur][1];

        // S^T = K Q^T : lane holds q=lr, k = t*16+lg*4+r
        f32x4 sa[4] = {};
#pragma unroll
        for (int t = 0; t < 4; ++t) {
            const char* kr = Kc + (t * 16 + lr) * 128;
            bf16x8 kf0 = *reinterpret_cast<const bf16x8*>(kr + ((lg * 16) ^ rmask));
            bf16x8 kf1 = *reinterpret_cast<const bf16x8*>(kr + ((64 + lg * 16) ^ rmask));
            sa[t] = mfma_16x16x32(kf0, qf[0], sa[t]);
            sa[t] = mfma_16x16x32(kf1, qf[1], sa[t]);
        }

        // softmax: p = exp2((s+bias)·log2e − smh·log2e); exponent ≤ ~0.006·smh, safe
#pragma unroll
        for (int t = 0; t < 4; ++t) {
            bf16x4 bv = *reinterpret_cast<const bf16x4*>(brow + kb * 64 + t * 16 + lg * 4);
            bf16x4 pb;
#pragma unroll
            for (int r = 0; r < 4; ++r) {
                float s = sa[t][r] + (float)bv[r];
                float p = exp2f(fmaf(s, LOG2E, cexp));
                lsum += p;
                pb[r] = (__bf16)p;
            }
            *reinterpret_cast<bf16x4*>(psb + ((t * 32 + lg * 8) ^ rmask)) = pb;
        }

        // O += P·V (Ps rows wave-private; lgkmcnt handles same-wave RAW)
        bf16x8 pf0 = *reinterpret_cast<const bf16x8*>(psb + ((lg * 16) ^ rmask));
        bf16x8 pf1 = *reinterpret_cast<const bf16x8*>(psb + ((64 + lg * 16) ^ rmask));
#pragma unroll
        for (int t = 0; t < 4; ++t) {
            const char* vr = Vc + (t * 16 + lr) * 128;
            bf16x8 vf0 = *reinterpret_cast<const bf16x8*>(vr + ((lg * 16) ^ rmask));
            bf16x8 vf1 = *reinterpret_cast<const bf16x8*>(vr + ((64 + lg * 16) ^ rmask));
            Oa[t] = mfma_16x16x32(pf0, vf0, Oa[t]);
            Oa[t] = mfma_16x16x32(pf1, vf1, Oa[t]);
        }

        if (kb < 31) write_lds(cur ^ 1); // write-late; dep on loads forces vmcnt
        cur ^= 1;
    }

    // reduce lsum over the 4 lg-groups (each q's partials live in lanes lr, lr+16, lr+32, lr+48)
    lsum += __shfl_xor(lsum, 16, 64);
    lsum += __shfl_xor(lsum, 32, 64);
    float inv[4];
#pragma unroll
    for (int r = 0; r < 4; ++r) inv[r] = 1.0f / __shfl(lsum, lg * 4 + r, 64);

#pragma unroll
    for (int t = 0; t < 4; ++t)
#pragma unroll
        for (int r = 0; r < 4; ++r) {
            const int row = qb * 64 + w * 16 + lg * 4 + r;
            float o = Oa[t][r] * inv[r];
            Octx[((size_t)(b * 2048 + row)) * 1024 + h * 64 + t * 16 + lr] = (__bf16)o;
        }
}

// ---------------- launch ----------------
extern "C" void kernel_launch(void* const* d_in, const int* in_sizes, int n_in,
                              void* d_out, int out_size, void* d_ws, size_t ws_size,
                              hipStream_t stream) {
    const float* x         = (const float*)d_in[0];
    const float* attn_bias = (const float*)d_in[1];
    const float* W_qkv     = (const float*)d_in[2];
    const float* q_bias    = (const float*)d_in[3];
    const float* v_bias    = (const float*)d_in[4];
    const float* scale_mul = (const float*)d_in[5];
    const float* W_proj    = (const float*)d_in[6];
    const float* b_proj    = (const float*)d_in[7];
    float* out = (float*)d_out;

    char* ws = (char*)d_ws;
    size_t off = 0;
    auto alloc = [&](size_t bytes) {
        void* p = ws + off;
        off = (off + bytes + 255) & ~(size_t)255;
        return p;
    };
    __bf16* xb     = (__bf16*)alloc((size_t)4096 * 1024 * 2);
    __bf16* wqkvb  = (__bf16*)alloc((size_t)3072 * 1024 * 2);
    __bf16* wprojb = (__bf16*)alloc((size_t)1024 * 1024 * 2);
    __bf16* qkvb   = (__bf16*)alloc((size_t)4096 * 3072 * 2);   // 24 MB
    __bf16* Qw     = (__bf16*)alloc((size_t)BB * HH * LL * DD * 2);
    __bf16* Kw     = (__bf16*)alloc((size_t)BB * HH * LL * DD * 2);
    __bf16* Vw     = (__bf16*)alloc((size_t)BB * HH * LL * DD * 2);
    __bf16* Oc     = (__bf16*)alloc((size_t)4096 * 1024 * 2);
    // alias: after qkv_norm consumes qkvb, reuse its space for bias_bf and Vt
    __bf16* bias_bf = qkvb;                                      // 8 MB
    __bf16* Vt      = qkvb + (size_t)2048 * 2048;                // 8 MB

    cvt_bf16_kernel<<<4096, 256, 0, stream>>>(x, xb, 4096 * 1024 / 4);
    cvt_bf16_kernel<<<3072, 256, 0, stream>>>(W_qkv, wqkvb, 3072 * 1024 / 4);
    cvt_bf16_kernel<<<1024, 256, 0, stream>>>(W_proj, wprojb, 1024 * 1024 / 4);

    gemm_bt_kernel<0><<<dim3(32, 24), 256, 0, stream>>>(
        xb, wqkvb, nullptr, qkvb, nullptr, 4096, 3072, 1024);

    qkv_norm_kernel<<<4096, 256, 0, stream>>>(qkvb, q_bias, v_bias, scale_mul, Qw, Kw, Vw);

    bias_prep_kernel<<<2048, 256, 0, stream>>>(attn_bias, bias_bf);
    v_transpose_kernel<<<dim3(32, 32), 256, 0, stream>>>(Vw, Vt);

    attn_kernel<<<dim3(32, 32), 256, 0, stream>>>(Qw, Kw, Vt, bias_bf, scale_mul, Oc);

    gemm_bt_kernel<1><<<dim3(32, 8), 256, 0, stream>>>(
        Oc, wprojb, out, nullptr, b_proj, 4096, 1024, 1024);
}